// Round 1
// baseline (192.453 us; speedup 1.0000x reference)
//
#include <hip/hip_runtime.h>
#include <hip/hip_bf16.h>

// MC3DAD geometry features: per-point kNN (k=5) covariance-trace curvature.
// B=8, N=4096, 3D points, f32 in / f32 out ([B,N] curvature).
//
// Faithfulness notes (threshold is 1.57e-4 vs max ref 7.87e-3):
//  - d2 = (sq_n + sq_m) - 2*dot computed with __f*_rn intrinsics to block
//    hipcc's default FMA contraction (must match numpy's mul-then-add).
//  - selection order = lexicographic (dist, index), dist = sqrt(max(d2,0)):
//    in-segment ascending scan with strict-< insertion gives (d2,idx) order;
//    the 20-entry merge re-ranks by IEEE __fsqrt_rn to honor sqrt-collapse
//    ties exactly like jax.lax.top_k on -dist.

constexpr int N_PTS   = 4096;
constexpr int BATCH   = 8;
constexpr int KNN     = 5;
constexpr int SEG     = 4;                 // candidate segments per query
constexpr int SEGLEN  = N_PTS / SEG;       // 1024
constexpr int QPB     = 64;                // queries per block
constexpr int NTHR    = QPB * SEG;         // 256
constexpr int MSTRIDE = SEG * KNN + 1;     // 21 (pad to break LDS stride)

__device__ __forceinline__ int swz(int j) { return j + (j >> 10); } // +16B per segment

__global__ __launch_bounds__(NTHR, 2)
void knn_trace_kernel(const float* __restrict__ pcd, float* __restrict__ trace_out)
{
    __shared__ float4 pts[N_PTS + SEG];          // {x,y,z,|p|^2}, swizzled
    __shared__ float  mdist[QPB][MSTRIDE];       // partial top-5 d2
    __shared__ int    midx [QPB][MSTRIDE];       // partial top-5 index

    const int b = blockIdx.y;
    const int t = threadIdx.x;
    const float* __restrict__ batch = pcd + (size_t)b * N_PTS * 3;

    // ---- stage batch into LDS, precompute |p|^2 = ((x*x + y*y) + z*z) ----
    #pragma unroll
    for (int i = 0; i < N_PTS / NTHR; ++i) {
        const int p = t + i * NTHR;
        const float x = batch[p * 3 + 0];
        const float y = batch[p * 3 + 1];
        const float z = batch[p * 3 + 2];
        const float sq = __fadd_rn(__fadd_rn(__fmul_rn(x, x), __fmul_rn(y, y)),
                                   __fmul_rn(z, z));
        pts[swz(p)] = make_float4(x, y, z, sq);
    }
    __syncthreads();

    // ---- per-thread top-5 over one 1024-candidate segment ----
    const int qi = t >> 2;                 // 0..63  query within block
    const int s  = t & 3;                  // 0..3   segment
    const int q  = blockIdx.x * QPB + qi;  // query index in batch
    const float4 qp = pts[swz(q)];

    float b0 = __builtin_inff(), b1 = b0, b2 = b0, b3 = b0, b4 = b0;
    int   n0 = 0x7fffffff, n1 = n0, n2 = n0, n3 = n0, n4 = n0;

    const int base = swz(s * SEGLEN);
    #pragma unroll 4
    for (int m = 0; m < SEGLEN; ++m) {
        const float4 c = pts[base + m];
        const float dot = __fadd_rn(__fadd_rn(__fmul_rn(qp.x, c.x),
                                              __fmul_rn(qp.y, c.y)),
                                    __fmul_rn(qp.z, c.z));
        const float dd = __fsub_rn(__fadd_rn(qp.w, c.w), __fmul_rn(2.0f, dot));
        if (dd < b4) {                     // strict <: earlier index wins ties
            const int j = s * SEGLEN + m;
            if (dd < b3) {
                b4 = b3; n4 = n3;
                if (dd < b2) {
                    b3 = b2; n3 = n2;
                    if (dd < b1) {
                        b2 = b1; n2 = n1;
                        if (dd < b0) { b1 = b0; n1 = n0; b0 = dd; n0 = j; }
                        else         { b1 = dd; n1 = j; }
                    } else { b2 = dd; n2 = j; }
                } else { b3 = dd; n3 = j; }
            } else { b4 = dd; n4 = j; }
        }
    }

    mdist[qi][s * KNN + 0] = b0;  midx[qi][s * KNN + 0] = n0;
    mdist[qi][s * KNN + 1] = b1;  midx[qi][s * KNN + 1] = n1;
    mdist[qi][s * KNN + 2] = b2;  midx[qi][s * KNN + 2] = n2;
    mdist[qi][s * KNN + 3] = b3;  midx[qi][s * KNN + 3] = n3;
    mdist[qi][s * KNN + 4] = b4;  midx[qi][s * KNN + 4] = n4;
    __syncthreads();

    // ---- merge 4x5 -> 5 (by (sqrt-dist, index)), covariance trace ----
    if (t < QPB) {
        float dl[SEG * KNN];
        int   il[SEG * KNN];
        #pragma unroll
        for (int e = 0; e < SEG * KNN; ++e) {
            dl[e] = __fsqrt_rn(fmaxf(mdist[t][e], 0.0f)); // reference dist
            il[e] = midx[t][e];
        }

        int sel[KNN];
        #pragma unroll
        for (int r = 0; r < KNN; ++r) {
            float bd = __builtin_inff();
            int   bi = 0x7fffffff;
            #pragma unroll
            for (int e = 0; e < SEG * KNN; ++e) {
                const bool better = (dl[e] < bd) || (dl[e] == bd && il[e] < bi);
                if (better) { bd = dl[e]; bi = il[e]; }
            }
            sel[r] = bi;
            #pragma unroll
            for (int e = 0; e < SEG * KNN; ++e)   // remove chosen (static idx)
                if (dl[e] == bd && il[e] == bi) dl[e] = __builtin_inff();
        }

        float nx[KNN], ny[KNN], nz[KNN];
        #pragma unroll
        for (int r = 0; r < KNN; ++r) {
            const float4 p = pts[swz(sel[r])];
            nx[r] = p.x; ny[r] = p.y; nz[r] = p.z;
        }

        // centroid = sequential sum / 5 (numpy order)
        float sx = nx[0], sy = ny[0], sz = nz[0];
        #pragma unroll
        for (int r = 1; r < KNN; ++r) {
            sx = __fadd_rn(sx, nx[r]);
            sy = __fadd_rn(sy, ny[r]);
            sz = __fadd_rn(sz, nz[r]);
        }
        const float cx = __fdiv_rn(sx, 5.0f);
        const float cy = __fdiv_rn(sy, 5.0f);
        const float cz = __fdiv_rn(sz, 5.0f);

        // diagonal of centered^T centered, sequential over k
        float sxx = 0.0f, syy = 0.0f, szz = 0.0f;
        #pragma unroll
        for (int r = 0; r < KNN; ++r) {
            const float dx = __fsub_rn(nx[r], cx);
            const float dy = __fsub_rn(ny[r], cy);
            const float dz = __fsub_rn(nz[r], cz);
            sxx = __fadd_rn(sxx, __fmul_rn(dx, dx));
            syy = __fadd_rn(syy, __fmul_rn(dy, dy));
            szz = __fadd_rn(szz, __fmul_rn(dz, dz));
        }
        // cov diag = s/4 (exact), trace = (xx + yy) + zz
        const float trace = __fadd_rn(__fadd_rn(__fmul_rn(sxx, 0.25f),
                                                __fmul_rn(syy, 0.25f)),
                                      __fmul_rn(szz, 0.25f));
        trace_out[(size_t)b * N_PTS + blockIdx.x * QPB + t] = trace;
    }
}

__global__ __launch_bounds__(256)
void curvature_kernel(const float* __restrict__ trace, float* __restrict__ out)
{
    __shared__ float red[256];
    const int b = blockIdx.x;
    const int t = threadIdx.x;
    const float* __restrict__ tr = trace + (size_t)b * N_PTS;

    float v[N_PTS / 256];
    float s = 0.0f;
    #pragma unroll
    for (int i = 0; i < N_PTS / 256; ++i) {
        v[i] = tr[t + i * 256];
        s += v[i];
    }
    red[t] = s;
    __syncthreads();
    #pragma unroll
    for (int o = 128; o > 0; o >>= 1) {
        if (t < o) red[t] += red[t + o];
        __syncthreads();
    }
    const float denom = red[0] + 1e-8f;

    float* __restrict__ ob = out + (size_t)b * N_PTS;
    #pragma unroll
    for (int i = 0; i < N_PTS / 256; ++i)
        ob[t + i * 256] = v[i] / denom;
}

extern "C" void kernel_launch(void* const* d_in, const int* in_sizes, int n_in,
                              void* d_out, int out_size, void* d_ws, size_t ws_size,
                              hipStream_t stream)
{
    const float* pcd = (const float*)d_in[0];   // [8,4096,3] f32
    float* trace = (float*)d_ws;                // [8,4096] f32 scratch
    float* out = (float*)d_out;                 // [8,4096] f32

    dim3 gridA(N_PTS / QPB, BATCH);             // 64 x 8 blocks
    knn_trace_kernel<<<gridA, NTHR, 0, stream>>>(pcd, trace);
    curvature_kernel<<<BATCH, 256, 0, stream>>>(trace, out);
}

// Round 2
// 176.988 us; speedup vs baseline: 1.0874x; 1.0874x over previous
//
#include <hip/hip_runtime.h>
#include <hip/hip_bf16.h>

// MC3DAD geometry features: per-point kNN (k=5) covariance-trace curvature.
// B=8, N=4096, f32. Round 2: Q=4 query register-blocking, branchless
// top-5 insert (cmp+cndmask chain, no divergence), 512-thread blocks
// (SEG=32 x SEGLEN=128) for 16 waves/CU, cross-lane butterfly merge on
// packed (sqrt-dist, idx) u64 keys (no merge LDS).
//
// Numerics (round-1 achieved absmax 0.0 — preserved):
//  - dd = (sq_n + sq_m) - 2*dot with __f*_rn ops (no FMA contraction),
//    identical op tree to numpy's expansion.
//  - scan keeps top-5 by raw dd (strict <, insertion-stable => (dd,idx)
//    order); final ranking by key = (bits(sqrt(max(dd,0)))<<32)|idx,
//    u64-lex == top_k(-dist) tie semantics.
//  - centroid / covariance trace replicated op-for-op from round 1.

typedef unsigned long long ull;

constexpr int N_PTS  = 4096;
constexpr int BATCH  = 8;
constexpr int KNN    = 5;
constexpr int SEG    = 32;              // candidate segments (lanes) per query group
constexpr int SEGLEN = N_PTS / SEG;     // 128
constexpr int QPB    = 64;              // queries per block
constexpr int Q      = 4;               // queries per thread
constexpr int NTHR   = 512;             // (QPB/Q) groups x SEG lanes

__device__ __forceinline__ int swz(int j) { return j + (j >> 7); } // +16B / 128 float4

__device__ __forceinline__ ull umin64(ull a, ull b) { return a < b ? a : b; }
__device__ __forceinline__ ull umax64(ull a, ull b) { return a < b ? b : a; }

// Branchless stable insert of (dd,idx) into ascending 5-list.
// Tie (dd equal): existing entry keeps the lower slot (earlier index wins).
__device__ __forceinline__ void push5(float dd, int idx,
                                      float d[KNN], int ix[KNN])
{
    float ad = dd; int ai = idx;
    #pragma unroll
    for (int p = 0; p < KNN - 1; ++p) {
        const bool lt = ad < d[p];
        const float md = lt ? ad : d[p];
        const int   mi = lt ? ai : ix[p];
        const float xd = lt ? d[p] : ad;
        const int   xi = lt ? ix[p] : ai;
        d[p] = md; ix[p] = mi; ad = xd; ai = xi;
    }
    const bool lt = ad < d[KNN - 1];
    d[KNN - 1]  = lt ? ad : d[KNN - 1];
    ix[KNN - 1] = lt ? ai : ix[KNN - 1];
}

// Merge two ascending sorted 5-lists (u64 lex keys) -> ascending top-5.
// merged[j] = min over i+k=j of max(a[i], b[k])  (with a[-1]=b[-1]=-inf).
__device__ __forceinline__ void merge5(ull a[KNN], const ull b[KNN])
{
    const ull r0 = umin64(a[0], b[0]);
    const ull r1 = umin64(umin64(a[1], b[1]), umax64(a[0], b[0]));
    const ull r2 = umin64(umin64(a[2], b[2]),
                          umin64(umax64(a[1], b[0]), umax64(a[0], b[1])));
    const ull r3 = umin64(umin64(a[3], b[3]),
                   umin64(umax64(a[2], b[0]),
                   umin64(umax64(a[1], b[1]), umax64(a[0], b[2]))));
    const ull r4 = umin64(umin64(a[4], b[4]),
                   umin64(umin64(umax64(a[3], b[0]), umax64(a[2], b[1])),
                          umin64(umax64(a[1], b[2]), umax64(a[0], b[3]))));
    a[0] = r0; a[1] = r1; a[2] = r2; a[3] = r3; a[4] = r4;
}

__global__ __launch_bounds__(NTHR, 4)
void knn_trace_kernel(const float* __restrict__ pcd, float* __restrict__ trace_out)
{
    __shared__ float4 pts[N_PTS + SEG];            // {x,y,z,|p|^2}, swizzled

    const int b = blockIdx.y;
    const int t = threadIdx.x;
    const float* __restrict__ batch = pcd + (size_t)b * N_PTS * 3;

    // ---- stage batch into LDS, |p|^2 = (x*x + y*y) + z*z ----
    #pragma unroll
    for (int i = 0; i < N_PTS / NTHR; ++i) {
        const int p = t + i * NTHR;
        const float x = batch[p * 3 + 0];
        const float y = batch[p * 3 + 1];
        const float z = batch[p * 3 + 2];
        const float sq = __fadd_rn(__fadd_rn(__fmul_rn(x, x), __fmul_rn(y, y)),
                                   __fmul_rn(z, z));
        pts[swz(p)] = make_float4(x, y, z, sq);
    }
    __syncthreads();

    const int g = t >> 5;                  // query group 0..15
    const int s = t & 31;                  // segment/lane  0..31
    const int qbase = blockIdx.x * QPB + g * Q;

    float4 qp[Q];
    #pragma unroll
    for (int j = 0; j < Q; ++j) qp[j] = pts[swz(qbase + j)];

    float dq[Q][KNN];
    int   iq[Q][KNN];
    #pragma unroll
    for (int j = 0; j < Q; ++j)
        #pragma unroll
        for (int r = 0; r < KNN; ++r) { dq[j][r] = __builtin_inff(); iq[j][r] = 0x7fffffff; }

    // ---- scan: 128 candidates x 4 queries per lane, branchless ----
    const int base = s * (SEGLEN + 1);     // swz(s*SEGLEN)
    #pragma unroll 4
    for (int m = 0; m < SEGLEN; ++m) {
        const float4 c = pts[base + m];
        const int cidx = (s << 7) + m;
        #pragma unroll
        for (int j = 0; j < Q; ++j) {
            const float dot = __fadd_rn(__fadd_rn(__fmul_rn(qp[j].x, c.x),
                                                  __fmul_rn(qp[j].y, c.y)),
                                        __fmul_rn(qp[j].z, c.z));
            const float dd = __fsub_rn(__fadd_rn(qp[j].w, c.w),
                                       __fmul_rn(2.0f, dot));
            push5(dd, cidx, dq[j], iq[j]);
        }
    }

    // ---- pack keys = (bits(sqrt(max(dd,0))) << 32) | idx, sort 5 ----
    ull key[Q][KNN];
    #pragma unroll
    for (int j = 0; j < Q; ++j) {
        #pragma unroll
        for (int r = 0; r < KNN; ++r) {
            const float dist = __fsqrt_rn(fmaxf(dq[j][r], 0.0f));
            key[j][r] = ((ull)__float_as_uint(dist) << 32) | (unsigned)iq[j][r];
        }
        // bubble network: restore full (dist,idx)-lex order after sqrt collapse
        #pragma unroll
        for (int i = 0; i < KNN - 1; ++i)
            #pragma unroll
            for (int p = 0; p < KNN - 1 - i; ++p) {
                const ull lo = umin64(key[j][p], key[j][p + 1]);
                const ull hi = umax64(key[j][p], key[j][p + 1]);
                key[j][p] = lo; key[j][p + 1] = hi;
            }
    }

    // ---- butterfly merge across the 32 segment lanes ----
    #pragma unroll
    for (int mask = 1; mask < SEG; mask <<= 1) {
        #pragma unroll
        for (int j = 0; j < Q; ++j) {
            ull o[KNN];
            #pragma unroll
            for (int r = 0; r < KNN; ++r) o[r] = __shfl_xor(key[j][r], mask);
            merge5(key[j], o);
        }
    }

    // ---- epilogue: lane s<4 handles query qbase+s ----
    if (s < Q) {
        ull kk[KNN];
        #pragma unroll
        for (int r = 0; r < KNN; ++r) {
            ull v = key[0][r];
            if (s == 1) v = key[1][r];
            if (s == 2) v = key[2][r];
            if (s == 3) v = key[3][r];
            kk[r] = v;
        }

        float nx[KNN], ny[KNN], nz[KNN];
        #pragma unroll
        for (int r = 0; r < KNN; ++r) {
            const int sel = (int)(kk[r] & 0xffffffffull);
            const float4 p = pts[swz(sel)];
            nx[r] = p.x; ny[r] = p.y; nz[r] = p.z;
        }

        // centroid = sequential sum / 5 (numpy order), round-1 verbatim
        float sx = nx[0], sy = ny[0], sz = nz[0];
        #pragma unroll
        for (int r = 1; r < KNN; ++r) {
            sx = __fadd_rn(sx, nx[r]);
            sy = __fadd_rn(sy, ny[r]);
            sz = __fadd_rn(sz, nz[r]);
        }
        const float cx = __fdiv_rn(sx, 5.0f);
        const float cy = __fdiv_rn(sy, 5.0f);
        const float cz = __fdiv_rn(sz, 5.0f);

        float sxx = 0.0f, syy = 0.0f, szz = 0.0f;
        #pragma unroll
        for (int r = 0; r < KNN; ++r) {
            const float dx = __fsub_rn(nx[r], cx);
            const float dy = __fsub_rn(ny[r], cy);
            const float dz = __fsub_rn(nz[r], cz);
            sxx = __fadd_rn(sxx, __fmul_rn(dx, dx));
            syy = __fadd_rn(syy, __fmul_rn(dy, dy));
            szz = __fadd_rn(szz, __fmul_rn(dz, dz));
        }
        const float trace = __fadd_rn(__fadd_rn(__fmul_rn(sxx, 0.25f),
                                                __fmul_rn(syy, 0.25f)),
                                      __fmul_rn(szz, 0.25f));
        trace_out[(size_t)b * N_PTS + qbase + s] = trace;
    }
}

// 64 blocks: 8 batches x 8 output slices. Each block redoes the batch
// reduction (bit-identical op tree to round 1) then writes its 512 outputs.
__global__ __launch_bounds__(256)
void curvature_kernel(const float* __restrict__ trace, float* __restrict__ out)
{
    __shared__ float red[256];
    const int b = blockIdx.x >> 3;
    const int c = blockIdx.x & 7;
    const int t = threadIdx.x;
    const float* __restrict__ tr = trace + (size_t)b * N_PTS;

    float s = 0.0f;
    #pragma unroll
    for (int i = 0; i < N_PTS / 256; ++i)
        s += tr[t + i * 256];
    red[t] = s;
    __syncthreads();
    #pragma unroll
    for (int o = 128; o > 0; o >>= 1) {
        if (t < o) red[t] += red[t + o];
        __syncthreads();
    }
    const float denom = red[0] + 1e-8f;

    float* __restrict__ ob = out + (size_t)b * N_PTS;
    const int x = c * 512 + t;
    ob[x]       = tr[x]       / denom;
    ob[x + 256] = tr[x + 256] / denom;
}

extern "C" void kernel_launch(void* const* d_in, const int* in_sizes, int n_in,
                              void* d_out, int out_size, void* d_ws, size_t ws_size,
                              hipStream_t stream)
{
    (void)in_sizes; (void)n_in; (void)out_size; (void)ws_size;
    const float* pcd = (const float*)d_in[0];   // [8,4096,3] f32
    float* trace = (float*)d_ws;                // [8,4096] f32 scratch
    float* out = (float*)d_out;                 // [8,4096] f32

    dim3 gridA(N_PTS / QPB, BATCH);             // 64 x 8 = 512 blocks
    knn_trace_kernel<<<gridA, NTHR, 0, stream>>>(pcd, trace);
    curvature_kernel<<<BATCH * 8, 256, 0, stream>>>(trace, out);
}

// Round 3
// 135.493 us; speedup vs baseline: 1.4204x; 1.3063x over previous
//
#include <hip/hip_runtime.h>
#include <hip/hip_bf16.h>

// MC3DAD kNN(k=5) covariance-trace curvature. B=8, N=4096, f32.
// Round 3: filtered scan. Per-lane lagged threshold tau (5th-best so far),
// fast fma distance test (inflated threshold => no false rejects), kept
// candidate indices appended to a per-lane LDS buffer via the always-write
// trick (store at slot cnt, advance cnt only on keep -> no branches, no
// exec-mask churn). Wave-collective drain when any lane nears full: exact
// numpy-tree dd recompute + branchless push5, tau tightens. Selection is
// bit-identical to rounds 1-2 (absmax 0.0): kept set is a superset of the
// exact strict-< insert set, drains preserve ascending index order, final
// ranking by packed (sqrt-dist, idx) u64 keys.

typedef unsigned long long ull;

constexpr int N_PTS  = 4096;
constexpr int BATCH  = 8;
constexpr int KNN    = 5;
constexpr int SEG    = 8;              // segments per query (lane>>3)
constexpr int SEGLEN = N_PTS / SEG;    // 512
constexpr int QPW    = 8;              // queries per wave (lane&7)
constexpr int NTHR   = 1024;           // 16 waves, 128 queries per block
constexpr int QPB    = (NTHR / 64) * QPW;
constexpr int KSLOT  = 16;             // per-lane buffer slots
constexpr int TRIG   = KSLOT - 4;      // drain if cnt > TRIG after a 4-group

__device__ __forceinline__ int swz(int j) { return j + (j >> 9); } // +16B/segment

__device__ __forceinline__ ull umin64(ull a, ull b) { return a < b ? a : b; }
__device__ __forceinline__ ull umax64(ull a, ull b) { return a < b ? b : a; }

// Branchless stable insert of (dd,idx) into ascending 5-list (strict <).
__device__ __forceinline__ void push5(float dd, int idx,
                                      float d[KNN], int ix[KNN])
{
    float ad = dd; int ai = idx;
    #pragma unroll
    for (int p = 0; p < KNN - 1; ++p) {
        const bool lt = ad < d[p];
        const float md = lt ? ad : d[p];
        const int   mi = lt ? ai : ix[p];
        const float xd = lt ? d[p] : ad;
        const int   xi = lt ? ix[p] : ai;
        d[p] = md; ix[p] = mi; ad = xd; ai = xi;
    }
    const bool lt = ad < d[KNN - 1];
    d[KNN - 1]  = lt ? ad : d[KNN - 1];
    ix[KNN - 1] = lt ? ai : ix[KNN - 1];
}

// Merge two ascending sorted 5-lists (u64 lex keys) -> ascending top-5.
__device__ __forceinline__ void merge5(ull a[KNN], const ull b[KNN])
{
    const ull r0 = umin64(a[0], b[0]);
    const ull r1 = umin64(umin64(a[1], b[1]), umax64(a[0], b[0]));
    const ull r2 = umin64(umin64(a[2], b[2]),
                          umin64(umax64(a[1], b[0]), umax64(a[0], b[1])));
    const ull r3 = umin64(umin64(a[3], b[3]),
                   umin64(umax64(a[2], b[0]),
                   umin64(umax64(a[1], b[1]), umax64(a[0], b[2]))));
    const ull r4 = umin64(umin64(a[4], b[4]),
                   umin64(umin64(umax64(a[3], b[0]), umax64(a[2], b[1])),
                          umin64(umax64(a[1], b[2]), umax64(a[0], b[3]))));
    a[0] = r0; a[1] = r1; a[2] = r2; a[3] = r3; a[4] = r4;
}

struct KnnShared {
    float4 pts[N_PTS + SEG];     // {x,y,z,|p|^2}, segment-swizzled (65,664 B)
    int    buf[KSLOT * NTHR];    // kept-candidate idx, lane-interleaved (65,536 B)
};

__device__ __forceinline__ void drain_buf(int& cnt, const float4 qp,
                                          float dq[KNN], int iq[KNN],
                                          float& tau_q,
                                          const float4* __restrict__ pts,
                                          const int* __restrict__ lanebuf)
{
    for (int j = 0; ; ++j) {
        if (!__any(j < cnt)) break;
        if (j < cnt) {
            const int idx = lanebuf[j * NTHR];
            const float4 c = pts[swz(idx)];
            // exact numpy tree: dd = (qw + cw) - 2*dot, dot = (xx + yy) + zz
            const float dot = __fadd_rn(__fadd_rn(__fmul_rn(qp.x, c.x),
                                                  __fmul_rn(qp.y, c.y)),
                                        __fmul_rn(qp.z, c.z));
            const float dd = __fsub_rn(__fadd_rn(qp.w, c.w),
                                       __fmul_rn(2.0f, dot));
            push5(dd, idx, dq, iq);
        }
    }
    cnt = 0;
    // lagged, inflated threshold: tau_q >= (live b4) - qw + margin, so the
    // fast-fma filter can never reject a true top-5 candidate.
    tau_q = __fsub_rn(dq[KNN - 1], qp.w) + 6e-5f;  // inf stays inf
}

__global__ __launch_bounds__(NTHR, 4)
void knn_trace_kernel(const float* __restrict__ pcd, float* __restrict__ trace_out)
{
    __shared__ KnnShared sh;

    const int b = blockIdx.y;
    const int t = threadIdx.x;
    const float* __restrict__ batch = pcd + (size_t)b * N_PTS * 3;

    // ---- stage batch into LDS, |p|^2 = (x*x + y*y) + z*z ----
    #pragma unroll
    for (int i = 0; i < N_PTS / NTHR; ++i) {
        const int p = t + i * NTHR;
        const float x = batch[p * 3 + 0];
        const float y = batch[p * 3 + 1];
        const float z = batch[p * 3 + 2];
        const float sq = __fadd_rn(__fadd_rn(__fmul_rn(x, x), __fmul_rn(y, y)),
                                   __fmul_rn(z, z));
        sh.pts[swz(p)] = make_float4(x, y, z, sq);
    }
    __syncthreads();

    const int lane = t & 63;
    const int wave = t >> 6;
    const int q    = lane & 7;             // query within wave
    const int s    = lane >> 3;            // segment
    const int qbase = blockIdx.x * QPB + wave * QPW;
    const float4 qp = sh.pts[swz(qbase + q)];

    float dq[KNN];
    int   iq[KNN];
    #pragma unroll
    for (int r = 0; r < KNN; ++r) { dq[r] = __builtin_inff(); iq[r] = 0x7fffffff; }

    const float4* __restrict__ seg = sh.pts + (s * SEGLEN + s);  // swz(s*SEGLEN)
    int* __restrict__ lanebuf = sh.buf + t;

    int   cnt   = 0;
    float tau_q = __builtin_inff();
    const int idx0 = s * SEGLEN;

    // ---- filtered scan: fast fma distance vs lagged threshold ----
    for (int m0 = 0; m0 < SEGLEN; m0 += 4) {
        #pragma unroll
        for (int u = 0; u < 4; ++u) {
            const float4 c = seg[m0 + u];
            const float t2 = fmaf(-2.0f,
                                  fmaf(qp.x, c.x,
                                       fmaf(qp.y, c.y, qp.z * c.z)),
                                  c.w);
            const bool keep = t2 < tau_q;
            lanebuf[cnt * NTHR] = idx0 + m0 + u;   // always-write
            cnt += keep ? 1 : 0;
        }
        if (__any(cnt > TRIG))
            drain_buf(cnt, qp, dq, iq, tau_q, sh.pts, lanebuf);
    }
    drain_buf(cnt, qp, dq, iq, tau_q, sh.pts, lanebuf);  // final

    // ---- pack keys = (bits(sqrt(max(dd,0))) << 32) | idx, sort 5 ----
    ull key[KNN];
    #pragma unroll
    for (int r = 0; r < KNN; ++r) {
        const float dist = __fsqrt_rn(fmaxf(dq[r], 0.0f));
        key[r] = ((ull)__float_as_uint(dist) << 32) | (unsigned)iq[r];
    }
    #pragma unroll
    for (int i = 0; i < KNN - 1; ++i)
        #pragma unroll
        for (int p = 0; p < KNN - 1 - i; ++p) {
            const ull lo = umin64(key[p], key[p + 1]);
            const ull hi = umax64(key[p], key[p + 1]);
            key[p] = lo; key[p + 1] = hi;
        }

    // ---- butterfly merge across the 8 segment groups (masks 8,16,32) ----
    #pragma unroll
    for (int mask = 8; mask < 64; mask <<= 1) {
        ull o[KNN];
        #pragma unroll
        for (int r = 0; r < KNN; ++r) o[r] = __shfl_xor(key[r], mask);
        merge5(key, o);
    }

    // ---- epilogue: lanes 0..7 of each wave own queries qbase+0..7 ----
    if (lane < 8) {
        float nx[KNN], ny[KNN], nz[KNN];
        #pragma unroll
        for (int r = 0; r < KNN; ++r) {
            const int sel = (int)(key[r] & 0xffffffffull);
            const float4 p = sh.pts[swz(sel)];
            nx[r] = p.x; ny[r] = p.y; nz[r] = p.z;
        }

        float sx = nx[0], sy = ny[0], sz = nz[0];
        #pragma unroll
        for (int r = 1; r < KNN; ++r) {
            sx = __fadd_rn(sx, nx[r]);
            sy = __fadd_rn(sy, ny[r]);
            sz = __fadd_rn(sz, nz[r]);
        }
        const float cx = __fdiv_rn(sx, 5.0f);
        const float cy = __fdiv_rn(sy, 5.0f);
        const float cz = __fdiv_rn(sz, 5.0f);

        float sxx = 0.0f, syy = 0.0f, szz = 0.0f;
        #pragma unroll
        for (int r = 0; r < KNN; ++r) {
            const float dx = __fsub_rn(nx[r], cx);
            const float dy = __fsub_rn(ny[r], cy);
            const float dz = __fsub_rn(nz[r], cz);
            sxx = __fadd_rn(sxx, __fmul_rn(dx, dx));
            syy = __fadd_rn(syy, __fmul_rn(dy, dy));
            szz = __fadd_rn(szz, __fmul_rn(dz, dz));
        }
        const float trace = __fadd_rn(__fadd_rn(__fmul_rn(sxx, 0.25f),
                                                __fmul_rn(syy, 0.25f)),
                                      __fmul_rn(szz, 0.25f));
        trace_out[(size_t)b * N_PTS + qbase + lane] = trace;
    }
}

// Unchanged from round 2 (passed with absmax 0.0) — keep the reduction tree
// bit-identical.
__global__ __launch_bounds__(256)
void curvature_kernel(const float* __restrict__ trace, float* __restrict__ out)
{
    __shared__ float red[256];
    const int b = blockIdx.x >> 3;
    const int c = blockIdx.x & 7;
    const int t = threadIdx.x;
    const float* __restrict__ tr = trace + (size_t)b * N_PTS;

    float s = 0.0f;
    #pragma unroll
    for (int i = 0; i < N_PTS / 256; ++i)
        s += tr[t + i * 256];
    red[t] = s;
    __syncthreads();
    #pragma unroll
    for (int o = 128; o > 0; o >>= 1) {
        if (t < o) red[t] += red[t + o];
        __syncthreads();
    }
    const float denom = red[0] + 1e-8f;

    float* __restrict__ ob = out + (size_t)b * N_PTS;
    const int x = c * 512 + t;
    ob[x]       = tr[x]       / denom;
    ob[x + 256] = tr[x + 256] / denom;
}

extern "C" void kernel_launch(void* const* d_in, const int* in_sizes, int n_in,
                              void* d_out, int out_size, void* d_ws, size_t ws_size,
                              hipStream_t stream)
{
    (void)in_sizes; (void)n_in; (void)out_size; (void)ws_size;
    const float* pcd = (const float*)d_in[0];   // [8,4096,3] f32
    float* trace = (float*)d_ws;                // [8,4096] f32 scratch
    float* out = (float*)d_out;                 // [8,4096] f32

    dim3 gridA(N_PTS / QPB, BATCH);             // 32 x 8 = 256 blocks (1/CU)
    knn_trace_kernel<<<gridA, NTHR, 0, stream>>>(pcd, trace);
    curvature_kernel<<<BATCH * 8, 256, 0, stream>>>(trace, out);
}